// Round 1
// baseline (1393.327 us; speedup 1.0000x reference)
//
#include <hip/hip_runtime.h>
#include <hip/hip_bf16.h>

#define NODES 100000
#define EDGES 1600000
#define NGRAPH 512
#define BINROWS 512   // rows per bin
#define NBINS 196     // ceil(NODES / 512)
#define BINCAP 12288  // staging slots per bin (mean 8192, sd ~90 -> 45 sigma margin)
#define CHUNK 4096    // edges per binPlace block
#define NCHUNKS ((EDGES + CHUNK - 1) / CHUNK)
#define VSS 72        // LDS row stride in shorts (144 B, 16B-aligned for b128)
#define ACCW 65       // f32 accumulator row stride (pad: bank = (dl+4c+k)%32)

using bf16 = __hip_bfloat16;
typedef long long ll;
using frag8 = __attribute__((ext_vector_type(8))) short;  // 8 bf16 (4 VGPRs)
using f32x4 = __attribute__((ext_vector_type(4))) float;

__device__ __forceinline__ float lrelu(float v) { return v > 0.0f ? v : 0.2f * v; }

__device__ __forceinline__ unsigned mapf(float f) {
    unsigned u = __float_as_uint(f);
    return (u & 0x80000000u) ? ~u : (u | 0x80000000u);
}
__device__ __forceinline__ float unmapf(unsigned u) {
    return __uint_as_float((u & 0x80000000u) ? (u ^ 0x80000000u) : ~u);
}

__device__ __forceinline__ int idx_at(const void* raw, int i, int f) {
    return f ? (int)((const ll*)raw)[i] : ((const int*)raw)[i];
}

__device__ __forceinline__ unsigned short tobf(float f) {
    bf16 h = __float2bfloat16(f);
    return *reinterpret_cast<unsigned short*>(&h);
}

__device__ __forceinline__ void lds_fadd(float* p, float v) {
    __hip_atomic_fetch_add(p, v, __ATOMIC_RELAXED, __HIP_MEMORY_SCOPE_WORKGROUP);
}

__global__ void sentinel_kernel(float* out, float v) {
    int i = blockIdx.x * blockDim.x + threadIdx.x;
    if (i < NGRAPH * 10) out[i] = v;
}

// single-pass staging build: per-block flag self-detect + local hist + global
// reservation into fixed-capacity bin slots. record = (src << 9) | (dst & 511).
__global__ void binPlace(const int* __restrict__ eiw, int* __restrict__ flag,
                         int* __restrict__ binCursor, unsigned* __restrict__ staging) {
    __shared__ unsigned recs[CHUNK];
    __shared__ unsigned char binsA[CHUNK];
    __shared__ int hist[NBINS], lstart[NBINS + 1], baseg[NBINS], lcur[NBINS];
    __shared__ int red[4];
    int t = threadIdx.x;
    int e0 = blockIdx.x * CHUNK;
    int eEnd = min(e0 + CHUNK, EDGES);
    // self-detect int64 storage from own chunk's odd words (ids<2^17: all-zero
    // iff int64; for int32 these are real node ids -> nonzero w.h.p.)
    int v = 0;
    for (int k = e0 + t; k < eEnd; k += 256) v |= eiw[2 * k + 1];
    for (int o = 32; o; o >>= 1) v |= __shfl_xor(v, o);
    if ((t & 63) == 0) red[t >> 6] = v;
    if (t < NBINS) { hist[t] = 0; lcur[t] = 0; }
    __syncthreads();
    int f = ((red[0] | red[1] | red[2] | red[3]) == 0) ? 1 : 0;
    if (blockIdx.x == 0 && t == 0) flag[0] = f;  // publish for downstream kernels
    const void* ei = (const void*)eiw;
    for (int i = e0 + t; i < eEnd; i += 256) {
        int s = idx_at(ei, i, f), d = idx_at(ei, EDGES + i, f);
        if ((unsigned)s < NODES && (unsigned)d < NODES) atomicAdd(&hist[d >> 9], 1);
    }
    __syncthreads();
    if (t == 0) {
        int acc = 0;
        for (int bb = 0; bb < NBINS; ++bb) {
            lstart[bb] = acc;
            acc += hist[bb];
        }
        lstart[NBINS] = acc;
    }
    __syncthreads();
    if (t < NBINS && hist[t] > 0) baseg[t] = atomicAdd(&binCursor[t], hist[t]);
    __syncthreads();
    for (int i = e0 + t; i < eEnd; i += 256) {
        int s = idx_at(ei, i, f), d = idx_at(ei, EDGES + i, f);
        if ((unsigned)s < NODES && (unsigned)d < NODES) {
            int bb = d >> 9;
            int p = lstart[bb] + atomicAdd(&lcur[bb], 1);
            recs[p] = ((unsigned)s << 9) | (unsigned)(d & 511);
            binsA[p] = (unsigned char)bb;
        }
    }
    __syncthreads();
    int nv = lstart[NBINS];
    for (int p = t; p < nv; p += 256) {
        int bb = binsA[p];
        int idx = baseg[bb] + (p - lstart[bb]);
        if (idx < BINCAP) staging[(size_t)bb * BINCAP + idx] = recs[p];
    }
}

// one block per bin: self-compute global offset (prefix over binCursor), local
// degree hist + scan -> row_ptr/dinv1/dinv2, scatter records into csr.
// csr record = (src << 6) | (dst & 63): dst low bits let the GCN layers do
// edge-parallel accumulation without per-row chain walking. src < 2^17 fits.
__global__ void csr_finalize(const unsigned* __restrict__ staging,
                             const int* __restrict__ binCursor, int* __restrict__ row_ptr,
                             float* __restrict__ dinv1, float* __restrict__ dinv2,
                             int* __restrict__ csr_src) {
    __shared__ int lhist[BINROWS];
    __shared__ int sc[256];
    __shared__ int startSh;
    int b = blockIdx.x, t = threadIdx.x;
    int cv = (t < NBINS) ? binCursor[t] : 0;
    sc[t] = (t < b) ? cv : 0;  // exclusive prefix mask
    __syncthreads();
    for (int o = 128; o; o >>= 1) {
        if (t < o) sc[t] += sc[t + o];
        __syncthreads();
    }
    if (t == 0) startSh = sc[0];
    __syncthreads();
    int myStart = startSh;
    int cnt = binCursor[b];
    if (b == NBINS - 1 && t == 0) row_ptr[NODES] = myStart + cnt;
    const unsigned* st = staging + (size_t)b * BINCAP;
    int r0 = b << 9;
    for (int j = t; j < BINROWS; j += 256) lhist[j] = 0;
    __syncthreads();
    for (int p = t; p < cnt; p += 256) atomicAdd(&lhist[st[p] & 511], 1);
    __syncthreads();
    int base = t * 2;
    int v0 = lhist[base], v1 = lhist[base + 1];
    int tsum = v0 + v1;
    sc[t] = tsum;
    __syncthreads();
    for (int o = 1; o < 256; o <<= 1) {
        int u = (t >= o) ? sc[t - o] : 0;
        __syncthreads();
        sc[t] += u;
        __syncthreads();
    }
    int excl = sc[t] - tsum;
    int ex0 = excl, ex1 = excl + v0;
#pragma unroll
    for (int k = 0; k < 2; ++k) {
        int row = r0 + base + k;
        int ex = k ? ex1 : ex0;
        int dgz = k ? v1 : v0;
        if (row < NODES) {
            row_ptr[row] = myStart + ex;
            float dg = (float)dgz;
            dinv1[row] = 1.0f / sqrtf(dg + 2.0f);
            dinv2[row] = 1.0f / sqrtf(dg + 1.0f);
        }
    }
    __syncthreads();
    lhist[base] = ex0;
    lhist[base + 1] = ex1;
    __syncthreads();
    for (int p = t; p < cnt; p += 256) {
        unsigned rec = st[p];
        int slot = atomicAdd(&lhist[rec & 511], 1);
        // (src<<6) | (row & 63): bin base is a multiple of 64, so rec&63 == dst&63
        csr_src[myStart + slot] = (int)(((rec >> 9) << 6) | (rec & 63));
    }
}

// xs = bf16(x * dinv1), vectorized, saturating grid
__global__ void prescale_x(const float* __restrict__ x, const float* __restrict__ dinv1,
                           bf16* __restrict__ xs) {
    int i = blockIdx.x * blockDim.x + threadIdx.x;
    if (i >= NODES * 16) return;
    int row = i >> 4;
    float4 xv = ((const float4*)x)[i];
    float d1 = dinv1[row];
    uint2 p;
    p.x = (unsigned)tobf(xv.x * d1) | ((unsigned)tobf(xv.y * d1) << 16);
    p.y = (unsigned)tobf(xv.z * d1) | ((unsigned)tobf(xv.w * d1) << 16);
    ((uint2*)xs)[i] = p;
}

// shared body, edge-parallel version:
//  1. stage W^T into Wt, zero the 64xACCW f32 accumulator (aliases Vs region)
//  2. edge loop: 16 lanes per edge stream the block's contiguous CSR slice;
//     fire-and-forget ds_add_f32 into accS[dl][*] -- no dependency chain, so
//     iterations pipeline freely (2-wide manual unroll for in-flight loads)
//  3. post-pass: self term + dinv scale + bf16 pack (reg-buffered across a
//     barrier because Vs aliases accS), then the verified 16x16x32 MFMA.
// acc[nt] C/D layout: col=lane&15, row=quad*4+reg (verified).
__device__ __forceinline__ void gcn_core(const uint2* __restrict__ feat4,
                                         const int* __restrict__ csr,
                                         const int* __restrict__ rp,
                                         const float* __restrict__ dinv, float selfw,
                                         const float* __restrict__ W, short* Vs, short* Wt,
                                         int rowBase, int lane, int wave, f32x4 (&acc)[4]) {
    float* accS = (float*)Vs;  // 64 * ACCW f32, aliases Vs region
    int t = wave * 64 + lane;
    for (int i = t; i < 4096; i += 256) {  // Wt[n][k] = W[k][n], bf16
        int k = i >> 6, n = i & 63;
        Wt[n * VSS + k] = (short)tobf(W[i]);
    }
    for (int i = t; i < 64 * ACCW; i += 256) accS[i] = 0.0f;
    __syncthreads();
    int eBeg = rp[rowBase];
    int eEnd = rp[min(rowBase + 64, NODES)];
    int g = t >> 4;        // 16 edge-groups per block
    int c = lane & 15;     // 8 B column slice within the feature row
    int e = eBeg + g;
    for (; e + 16 < eEnd; e += 32) {
        unsigned rec0 = (unsigned)csr[e];
        unsigned rec1 = (unsigned)csr[e + 16];
        uint2 u0 = feat4[(size_t)(rec0 >> 6) * 16 + c];
        uint2 u1 = feat4[(size_t)(rec1 >> 6) * 16 + c];
        float* ap0 = accS + (rec0 & 63) * ACCW + (c << 2);
        float* ap1 = accS + (rec1 & 63) * ACCW + (c << 2);
        lds_fadd(ap0 + 0, __uint_as_float(u0.x << 16));
        lds_fadd(ap0 + 1, __uint_as_float(u0.x & 0xffff0000u));
        lds_fadd(ap0 + 2, __uint_as_float(u0.y << 16));
        lds_fadd(ap0 + 3, __uint_as_float(u0.y & 0xffff0000u));
        lds_fadd(ap1 + 0, __uint_as_float(u1.x << 16));
        lds_fadd(ap1 + 1, __uint_as_float(u1.x & 0xffff0000u));
        lds_fadd(ap1 + 2, __uint_as_float(u1.y << 16));
        lds_fadd(ap1 + 3, __uint_as_float(u1.y & 0xffff0000u));
    }
    if (e < eEnd) {
        unsigned rec0 = (unsigned)csr[e];
        uint2 u0 = feat4[(size_t)(rec0 >> 6) * 16 + c];
        float* ap0 = accS + (rec0 & 63) * ACCW + (c << 2);
        lds_fadd(ap0 + 0, __uint_as_float(u0.x << 16));
        lds_fadd(ap0 + 1, __uint_as_float(u0.x & 0xffff0000u));
        lds_fadd(ap0 + 2, __uint_as_float(u0.y << 16));
        lds_fadd(ap0 + 3, __uint_as_float(u0.y & 0xffff0000u));
    }
    __syncthreads();
    // post-pass: each lane (q,c) handles rows q*4+i of its wave's 16-row slab
    int q = lane >> 4;
    uint2 packed[4];
#pragma unroll
    for (int i = 0; i < 4; ++i) {
        int rloc = wave * 16 + q * 4 + i;
        int grow = rowBase + rloc;
        const float* ap = accS + rloc * ACCW + (c << 2);
        float v0 = ap[0], v1 = ap[1], v2 = ap[2], v3 = ap[3];
        float dv = 0.0f;
        uint2 us = make_uint2(0u, 0u);
        if (grow < NODES) {
            dv = dinv[grow];
            us = feat4[(size_t)grow * 16 + c];
        }
        v0 = dv * (v0 + selfw * __uint_as_float(us.x << 16));
        v1 = dv * (v1 + selfw * __uint_as_float(us.x & 0xffff0000u));
        v2 = dv * (v2 + selfw * __uint_as_float(us.y << 16));
        v3 = dv * (v3 + selfw * __uint_as_float(us.y & 0xffff0000u));
        packed[i].x = (unsigned)tobf(v0) | ((unsigned)tobf(v1) << 16);
        packed[i].y = (unsigned)tobf(v2) | ((unsigned)tobf(v3) << 16);
    }
    __syncthreads();  // all accS reads done before Vs overwrites the region
#pragma unroll
    for (int i = 0; i < 4; ++i) {
        int rloc = wave * 16 + q * 4 + i;
        *(uint2*)(Vs + (size_t)rloc * VSS + (c << 2)) = packed[i];
    }
    __syncthreads();
    frag8 afr[2];
    int m = lane & 15;
#pragma unroll
    for (int ks = 0; ks < 2; ++ks)
        afr[ks] = *(frag8*)(Vs + (size_t)(wave * 16 + m) * VSS + q * 8 + ks * 32);
#pragma unroll
    for (int nt = 0; nt < 4; ++nt) {
        f32x4 a = {0.f, 0.f, 0.f, 0.f};
#pragma unroll
        for (int ks = 0; ks < 2; ++ks) {
            frag8 bfr = *(frag8*)(Wt + (size_t)(nt * 16 + m) * VSS + q * 8 + ks * 32);
            a = __builtin_amdgcn_mfma_f32_16x16x32_bf16(afr[ks], bfr, a, 0, 0, 0);
        }
        acc[nt] = a;
    }
}

// layer1: gather + MFMA + bias + LN + leaky -> h1s = h1*dinv2 (bf16)
__global__ void __launch_bounds__(256, 2)
gcn1_fused(const uint2* __restrict__ xs4, const int* __restrict__ csr,
           const int* __restrict__ rp, const float* __restrict__ dinv1,
           const float* __restrict__ dinv2, const float* __restrict__ W1,
           const float* __restrict__ b1, const float* __restrict__ lng,
           const float* __restrict__ lnb, bf16* __restrict__ h1s) {
    __shared__ __align__(16) short sm[64 * ACCW * 2 + 64 * VSS];  // accS/Vs | Wt
    short* Vs = sm;
    short* Wt = sm + 64 * ACCW * 2;
    int lane = threadIdx.x & 63, wave = threadIdx.x >> 6;
    int rowBase = blockIdx.x * 64;
    f32x4 acc[4];
    gcn_core(xs4, csr, rp, dinv1, 2.0f, W1, Vs, Wt, rowBase, lane, wave, acc);
    int c = lane & 15, q = lane >> 4;
    float bc[4], lg[4], lb[4];
#pragma unroll
    for (int nt = 0; nt < 4; ++nt) {
        bc[nt] = b1[nt * 16 + c];
        lg[nt] = lng[nt * 16 + c];
        lb[nt] = lnb[nt * 16 + c];
    }
#pragma unroll
    for (int r = 0; r < 4; ++r) {
        int grow = rowBase + wave * 16 + q * 4 + r;
        float v0 = acc[0][r] + bc[0], v1 = acc[1][r] + bc[1];
        float v2 = acc[2][r] + bc[2], v3 = acc[3][r] + bc[3];
        float s = v0 + v1 + v2 + v3;
        for (int o = 1; o < 16; o <<= 1) s += __shfl_xor(s, o);
        float mu = s * (1.0f / 64.0f);
        float d0 = v0 - mu, d1 = v1 - mu, d2 = v2 - mu, d3 = v3 - mu;
        float qq = d0 * d0 + d1 * d1 + d2 * d2 + d3 * d3;
        for (int o = 1; o < 16; o <<= 1) qq += __shfl_xor(qq, o);
        float rstd = 1.0f / sqrtf(qq * (1.0f / 64.0f) + 1e-5f);
        if (grow < NODES) {
            float d2v = dinv2[grow];
            bf16* dst = h1s + (size_t)grow * 64 + c;
            dst[0]  = __float2bfloat16(lrelu(d0 * rstd * lg[0] + lb[0]) * d2v);
            dst[16] = __float2bfloat16(lrelu(d1 * rstd * lg[1] + lb[1]) * d2v);
            dst[32] = __float2bfloat16(lrelu(d2 * rstd * lg[2] + lb[2]) * d2v);
            dst[48] = __float2bfloat16(lrelu(d3 * rstd * lg[3] + lb[3]) * d2v);
        }
    }
}

// layer2: gather + MFMA + bias + leaky + run-merged max-pool
__global__ void __launch_bounds__(256, 2)
gcn2_fused(const uint2* __restrict__ h1s4, const int* __restrict__ csr,
           const int* __restrict__ rp, const float* __restrict__ dinv2,
           const float* __restrict__ W2, const float* __restrict__ b2,
           const void* __restrict__ batch, const int* __restrict__ flag,
           unsigned* __restrict__ pooled) {
    __shared__ __align__(16) short sm[64 * ACCW * 2 + 64 * VSS];  // accS/Vs/P | Wt
    __shared__ int gsh[64];
    short* Vs = sm;
    short* Wt = sm + 64 * ACCW * 2;
    int t = threadIdx.x, lane = t & 63, wave = t >> 6;
    int rowBase = blockIdx.x * 64;
    if (t < 64) {
        int row = rowBase + t;
        gsh[t] = (row < NODES) ? idx_at(batch, row, flag[0]) : -1;
    }
    f32x4 acc[4];
    gcn_core(h1s4, csr, rp, dinv2, 1.0f, W2, Vs, Wt, rowBase, lane, wave, acc);
    int c = lane & 15, q = lane >> 4;
    float bc[4];
#pragma unroll
    for (int nt = 0; nt < 4; ++nt) bc[nt] = b2[nt * 16 + c];
    __syncthreads();
    float* P = (float*)sm;  // 64 x 65 fp32 pool buffer (fits in accS/Vs region)
#pragma unroll
    for (int r = 0; r < 4; ++r) {
        int mloc = wave * 16 + q * 4 + r;
#pragma unroll
        for (int nt = 0; nt < 4; ++nt)
            P[(size_t)mloc * 65 + nt * 16 + c] = lrelu(acc[nt][r] + bc[nt]);
    }
    __syncthreads();
    if (wave == 0) {
        float m = P[lane];
        int gc = gsh[0];
        for (int r = 1; r < 64; ++r) {
            int gr = gsh[r];
            float ar = P[(size_t)r * 65 + lane];
            if (gr == gc) {
                m = fmaxf(m, ar);
            } else {
                if ((unsigned)gc < NGRAPH) atomicMax(&pooled[gc * 64 + lane], mapf(m));
                gc = gr;
                m = ar;
            }
        }
        if ((unsigned)gc < NGRAPH) atomicMax(&pooled[gc * 64 + lane], mapf(m));
    }
}

// head: z = pooled@W3+b3; LN; leaky; z@W4+b4; softmax. One block per graph.
__global__ void head_kernel(const unsigned* __restrict__ pooled, const float* __restrict__ W3,
                            const float* __restrict__ b3, const float* __restrict__ g2,
                            const float* __restrict__ be2, const float* __restrict__ W4,
                            const float* __restrict__ b4, float* __restrict__ out) {
    __shared__ float prow[64];
    __shared__ float z[768];
    __shared__ float rs[4], rss[4];
    __shared__ float mu_s, rstd_s;
    __shared__ float red[10];
    int t = threadIdx.x, gI = blockIdx.x;
    if (t < 64) prow[t] = unmapf(pooled[gI * 64 + t]);
    __syncthreads();
    for (int c = t; c < 768; c += 256) {
        float acc = b3[c];
#pragma unroll 16
        for (int k = 0; k < 64; ++k) acc += prow[k] * W3[k * 768 + c];
        z[c] = acc;
    }
    __syncthreads();
    float s = 0.0f, ss = 0.0f;
    for (int c = t; c < 768; c += 256) {
        float v = z[c];
        s += v;
        ss += v * v;
    }
    for (int o = 32; o; o >>= 1) {
        s += __shfl_xor(s, o);
        ss += __shfl_xor(ss, o);
    }
    if ((t & 63) == 0) { rs[t >> 6] = s; rss[t >> 6] = ss; }
    __syncthreads();
    if (t == 0) {
        float S = rs[0] + rs[1] + rs[2] + rs[3];
        float SS = rss[0] + rss[1] + rss[2] + rss[3];
        float mu = S * (1.0f / 768.0f);
        float var = SS * (1.0f / 768.0f) - mu * mu;
        mu_s = mu;
        rstd_s = 1.0f / sqrtf(fmaxf(var, 0.0f) + 1e-5f);
    }
    __syncthreads();
    for (int c = t; c < 768; c += 256) {
        float y = (z[c] - mu_s) * rstd_s * g2[c] + be2[c];
        z[c] = lrelu(y);
    }
    if (t < 10) red[t] = 0.0f;
    __syncthreads();
    float p[10];
#pragma unroll
    for (int c = 0; c < 10; ++c) p[c] = 0.0f;
    for (int k = t; k < 768; k += 256) {
        float zv = z[k];
#pragma unroll
        for (int c = 0; c < 10; ++c) p[c] += zv * W4[k * 10 + c];
    }
#pragma unroll
    for (int c = 0; c < 10; ++c) atomicAdd(&red[c], p[c]);
    __syncthreads();
    if (t == 0) {
        float l[10], m = -1e30f;
#pragma unroll
        for (int c = 0; c < 10; ++c) {
            l[c] = red[c] + b4[c];
            m = fmaxf(m, l[c]);
        }
        float sum = 0.0f;
#pragma unroll
        for (int c = 0; c < 10; ++c) {
            l[c] = expf(l[c] - m);
            sum += l[c];
        }
        float inv = 1.0f / sum;
#pragma unroll
        for (int c = 0; c < 10; ++c) out[gI * 10 + c] = l[c] * inv;
    }
}

extern "C" void kernel_launch(void* const* d_in, const int* in_sizes, int n_in,
                              void* d_out, int out_size, void* d_ws, size_t ws_size,
                              hipStream_t stream) {
    const size_t REQUIRED = (size_t)NODES * 64 * 2 * 2    // xs + h1s (staging aliases h1s)
                          + (size_t)EDGES * 4             // csr_src
                          + (size_t)(NODES + 1) * 4       // row_ptr
                          + (size_t)NODES * 4 * 2         // dinv1, dinv2
                          + (size_t)NBINS * 4             // binCursor
                          + (size_t)NGRAPH * 64 * 4       // pooled
                          + 16;                           // flag
    if (ws_size < REQUIRED) {
        sentinel_kernel<<<20, 256, 0, stream>>>((float*)d_out, 64.0f);
        return;
    }

    const float* x = (const float*)d_in[0];
    const int* eiw = (const int*)d_in[1];
    const void* batch = d_in[2];
    const float* W1 = (const float*)d_in[3];
    const float* b1 = (const float*)d_in[4];
    const float* lng = (const float*)d_in[5];
    const float* lnb = (const float*)d_in[6];
    const float* W2 = (const float*)d_in[7];
    const float* b2 = (const float*)d_in[8];
    const float* W3 = (const float*)d_in[9];
    const float* b3 = (const float*)d_in[10];
    const float* g2 = (const float*)d_in[11];
    const float* be2 = (const float*)d_in[12];
    const float* W4 = (const float*)d_in[13];
    const float* b4 = (const float*)d_in[14];

    bf16* xs = (bf16*)d_ws;                               // N*64 bf16
    bf16* h1s = xs + (size_t)NODES * 64;                  // N*64 bf16 (12.8 MB)
    unsigned* staging = (unsigned*)h1s;                   // NBINS*BINCAP*4 = 9.63 MB alias
    int* csr_src = (int*)(h1s + (size_t)NODES * 64);      // E
    int* row_ptr = csr_src + EDGES;                       // N+1
    float* dinv1 = (float*)(row_ptr + NODES + 1);         // N
    float* dinv2 = dinv1 + NODES;                         // N
    int* binCursor = (int*)(dinv2 + NODES);               // NBINS
    unsigned* pooled = (unsigned*)(binCursor + NBINS);    // G*64
    int* flag = (int*)(pooled + NGRAPH * 64);             // 1

    // pooled sentinel = 0 (0x00000000 < mapf(v) for every real float v)
    hipMemsetAsync(binCursor, 0, (size_t)NBINS * 4, stream);
    hipMemsetAsync(pooled, 0, (size_t)NGRAPH * 64 * 4, stream);

    // staging build (single edge-pass kernel; fixed-capacity bin slots)
    binPlace<<<NCHUNKS, 256, 0, stream>>>(eiw, flag, binCursor, staging);
    csr_finalize<<<NBINS, 256, 0, stream>>>(staging, binCursor, row_ptr, dinv1, dinv2,
                                            csr_src);
    prescale_x<<<(NODES * 16 + 255) / 256, 256, 0, stream>>>(x, dinv1, xs);

    // fused layers: 64 rows/block, edge-parallel LDS-atomic gather + MFMA
    gcn1_fused<<<(NODES + 63) / 64, 256, 0, stream>>>((const uint2*)xs, csr_src, row_ptr,
                                                      dinv1, dinv2, W1, b1, lng, lnb, h1s);
    gcn2_fused<<<(NODES + 63) / 64, 256, 0, stream>>>((const uint2*)h1s, csr_src, row_ptr,
                                                      dinv2, W2, b2, batch, flag, pooled);

    // head
    head_kernel<<<NGRAPH, 256, 0, stream>>>(pooled, W3, b3, g2, be2, W4, b4, (float*)d_out);
}

// Round 3
// 371.180 us; speedup vs baseline: 3.7538x; 3.7538x over previous
//
#include <hip/hip_runtime.h>
#include <hip/hip_bf16.h>

#define NODES 100000
#define EDGES 1600000
#define NGRAPH 512
#define BINROWS 512   // rows per bin
#define NBINS 196     // ceil(NODES / 512)
#define BINCAP 12288  // staging slots per bin (mean 8192, sd ~90 -> 45 sigma margin)
#define CHUNK 4096    // edges per binPlace block
#define NCHUNKS ((EDGES + CHUNK - 1) / CHUNK)
#define VSS 72        // LDS row stride in shorts (144 B, 16B-aligned for b128)
#define ZROW NODES    // padded zero feature row for inactive edge slots

using bf16 = __hip_bfloat16;
typedef long long ll;
using frag8 = __attribute__((ext_vector_type(8))) short;  // 8 bf16 (4 VGPRs)
using f32x4 = __attribute__((ext_vector_type(4))) float;

__device__ __forceinline__ float lrelu(float v) { return v > 0.0f ? v : 0.2f * v; }

__device__ __forceinline__ unsigned mapf(float f) {
    unsigned u = __float_as_uint(f);
    return (u & 0x80000000u) ? ~u : (u | 0x80000000u);
}
__device__ __forceinline__ float unmapf(unsigned u) {
    return __uint_as_float((u & 0x80000000u) ? (u ^ 0x80000000u) : ~u);
}

__device__ __forceinline__ int idx_at(const void* raw, int i, int f) {
    return f ? (int)((const ll*)raw)[i] : ((const int*)raw)[i];
}

__device__ __forceinline__ unsigned short tobf(float f) {
    bf16 h = __float2bfloat16(f);
    return *reinterpret_cast<unsigned short*>(&h);
}

__global__ void sentinel_kernel(float* out, float v) {
    int i = blockIdx.x * blockDim.x + threadIdx.x;
    if (i < NGRAPH * 10) out[i] = v;
}

// single-pass staging build: per-block flag self-detect + local hist + global
// reservation into fixed-capacity bin slots. record = (src << 9) | (dst & 511).
__global__ void binPlace(const int* __restrict__ eiw, int* __restrict__ flag,
                         int* __restrict__ binCursor, unsigned* __restrict__ staging) {
    __shared__ unsigned recs[CHUNK];
    __shared__ unsigned char binsA[CHUNK];
    __shared__ int hist[NBINS], lstart[NBINS + 1], baseg[NBINS], lcur[NBINS];
    __shared__ int red[4];
    int t = threadIdx.x;
    int e0 = blockIdx.x * CHUNK;
    int eEnd = min(e0 + CHUNK, EDGES);
    // self-detect int64 storage from own chunk's odd words (ids<2^17: all-zero
    // iff int64; for int32 these are real node ids -> nonzero w.h.p.)
    int v = 0;
    for (int k = e0 + t; k < eEnd; k += 256) v |= eiw[2 * k + 1];
    for (int o = 32; o; o >>= 1) v |= __shfl_xor(v, o);
    if ((t & 63) == 0) red[t >> 6] = v;
    if (t < NBINS) { hist[t] = 0; lcur[t] = 0; }
    __syncthreads();
    int f = ((red[0] | red[1] | red[2] | red[3]) == 0) ? 1 : 0;
    if (blockIdx.x == 0 && t == 0) flag[0] = f;  // publish for downstream kernels
    const void* ei = (const void*)eiw;
    for (int i = e0 + t; i < eEnd; i += 256) {
        int s = idx_at(ei, i, f), d = idx_at(ei, EDGES + i, f);
        if ((unsigned)s < NODES && (unsigned)d < NODES) atomicAdd(&hist[d >> 9], 1);
    }
    __syncthreads();
    if (t == 0) {
        int acc = 0;
        for (int bb = 0; bb < NBINS; ++bb) {
            lstart[bb] = acc;
            acc += hist[bb];
        }
        lstart[NBINS] = acc;
    }
    __syncthreads();
    if (t < NBINS && hist[t] > 0) baseg[t] = atomicAdd(&binCursor[t], hist[t]);
    __syncthreads();
    for (int i = e0 + t; i < eEnd; i += 256) {
        int s = idx_at(ei, i, f), d = idx_at(ei, EDGES + i, f);
        if ((unsigned)s < NODES && (unsigned)d < NODES) {
            int bb = d >> 9;
            int p = lstart[bb] + atomicAdd(&lcur[bb], 1);
            recs[p] = ((unsigned)s << 9) | (unsigned)(d & 511);
            binsA[p] = (unsigned char)bb;
        }
    }
    __syncthreads();
    int nv = lstart[NBINS];
    for (int p = t; p < nv; p += 256) {
        int bb = binsA[p];
        int idx = baseg[bb] + (p - lstart[bb]);
        if (idx < BINCAP) staging[(size_t)bb * BINCAP + idx] = recs[p];
    }
}

// one block per bin: self-compute global offset (prefix over binCursor), local
// degree hist + scan -> row_ptr/dinv1/dinv2, scatter src into csr_src.
__global__ void csr_finalize(const unsigned* __restrict__ staging,
                             const int* __restrict__ binCursor, int* __restrict__ row_ptr,
                             float* __restrict__ dinv1, float* __restrict__ dinv2,
                             int* __restrict__ csr_src) {
    __shared__ int lhist[BINROWS];
    __shared__ int sc[256];
    __shared__ int startSh;
    int b = blockIdx.x, t = threadIdx.x;
    int cv = (t < NBINS) ? binCursor[t] : 0;
    sc[t] = (t < b) ? cv : 0;  // exclusive prefix mask
    __syncthreads();
    for (int o = 128; o; o >>= 1) {
        if (t < o) sc[t] += sc[t + o];
        __syncthreads();
    }
    if (t == 0) startSh = sc[0];
    __syncthreads();
    int myStart = startSh;
    int cnt = binCursor[b];
    if (b == NBINS - 1 && t == 0) row_ptr[NODES] = myStart + cnt;
    const unsigned* st = staging + (size_t)b * BINCAP;
    int r0 = b << 9;
    for (int j = t; j < BINROWS; j += 256) lhist[j] = 0;
    __syncthreads();
    for (int p = t; p < cnt; p += 256) atomicAdd(&lhist[st[p] & 511], 1);
    __syncthreads();
    int base = t * 2;
    int v0 = lhist[base], v1 = lhist[base + 1];
    int tsum = v0 + v1;
    sc[t] = tsum;
    __syncthreads();
    for (int o = 1; o < 256; o <<= 1) {
        int u = (t >= o) ? sc[t - o] : 0;
        __syncthreads();
        sc[t] += u;
        __syncthreads();
    }
    int excl = sc[t] - tsum;
    int ex0 = excl, ex1 = excl + v0;
#pragma unroll
    for (int k = 0; k < 2; ++k) {
        int row = r0 + base + k;
        int ex = k ? ex1 : ex0;
        int dgz = k ? v1 : v0;
        if (row < NODES) {
            row_ptr[row] = myStart + ex;
            float dg = (float)dgz;
            dinv1[row] = 1.0f / sqrtf(dg + 2.0f);
            dinv2[row] = 1.0f / sqrtf(dg + 1.0f);
        }
    }
    __syncthreads();
    lhist[base] = ex0;
    lhist[base + 1] = ex1;
    __syncthreads();
    for (int p = t; p < cnt; p += 256) {
        unsigned rec = st[p];
        int slot = atomicAdd(&lhist[rec & 511], 1);
        csr_src[myStart + slot] = (int)(rec >> 9);
    }
}

// xs = bf16(x * dinv1), vectorized; also zeroes the ZROW pad row of xs and h1s
__global__ void prescale_x(const float* __restrict__ x, const float* __restrict__ dinv1,
                           bf16* __restrict__ xs, bf16* __restrict__ h1s) {
    int i = blockIdx.x * blockDim.x + threadIdx.x;
    if (i >= (NODES + 1) * 16) return;
    if (i >= NODES * 16) {  // ZROW pad for both feature tables
        uint2 z = make_uint2(0u, 0u);
        ((uint2*)xs)[i] = z;
        ((uint2*)h1s)[i] = z;
        return;
    }
    int row = i >> 4;
    float4 xv = ((const float4*)x)[i];
    float d1 = dinv1[row];
    uint2 p;
    p.x = (unsigned)tobf(xv.x * d1) | ((unsigned)tobf(xv.y * d1) << 16);
    p.y = (unsigned)tobf(xv.z * d1) | ((unsigned)tobf(xv.w * d1) << 16);
    ((uint2*)xs)[i] = p;
}

// one 8-edge step of one row-chain: 8-lane group o loads edge (j+o)'s source id
// (broadcast-coalesced, no shfl) and its 16B feature slice; inactive slots read
// ZROW (zeros) so the accumulate needs no per-lane predication.
__device__ __forceinline__ void chain_step(const uint4* __restrict__ feat16,
                                           const int* __restrict__ csr, int beg, int cnt,
                                           int j, int o, int c, float (&a)[8]) {
    if (j < cnt) {  // wave-uniform branch
        int eo = j + o;
        int idx = (eo < cnt) ? csr[beg + eo] : ZROW;
        uint4 u = feat16[(size_t)idx * 8 + c];
        a[0] += __uint_as_float(u.x << 16);
        a[1] += __uint_as_float(u.x & 0xffff0000u);
        a[2] += __uint_as_float(u.y << 16);
        a[3] += __uint_as_float(u.y & 0xffff0000u);
        a[4] += __uint_as_float(u.z << 16);
        a[5] += __uint_as_float(u.z & 0xffff0000u);
        a[6] += __uint_as_float(u.w << 16);
        a[7] += __uint_as_float(u.w & 0xffff0000u);
    }
}

__device__ __forceinline__ void butterfly8(float (&a)[8]) {
#pragma unroll
    for (int k = 0; k < 8; ++k) {
        a[k] += __shfl_xor(a[k], 8);
        a[k] += __shfl_xor(a[k], 16);
        a[k] += __shfl_xor(a[k], 32);
    }
}

// self term + dinv scale + bf16 pack + Vs store for one row (lanes o==0, c=0..7)
__device__ __forceinline__ void finalize_row(const uint4* __restrict__ feat16,
                                             const float* __restrict__ dinv, float selfw,
                                             short* Vs, int rowBase, int rloc, int c,
                                             const float (&a)[8]) {
    int grow = rowBase + rloc;
    float dv = 0.0f;
    uint4 us = make_uint4(0u, 0u, 0u, 0u);
    if (grow < NODES) {
        dv = dinv[grow];
        us = feat16[(size_t)grow * 8 + c];
    }
    float v0 = dv * (a[0] + selfw * __uint_as_float(us.x << 16));
    float v1 = dv * (a[1] + selfw * __uint_as_float(us.x & 0xffff0000u));
    float v2 = dv * (a[2] + selfw * __uint_as_float(us.y << 16));
    float v3 = dv * (a[3] + selfw * __uint_as_float(us.y & 0xffff0000u));
    float v4 = dv * (a[4] + selfw * __uint_as_float(us.z << 16));
    float v5 = dv * (a[5] + selfw * __uint_as_float(us.z & 0xffff0000u));
    float v6 = dv * (a[6] + selfw * __uint_as_float(us.w << 16));
    float v7 = dv * (a[7] + selfw * __uint_as_float(us.w & 0xffff0000u));
    uint4 pk;
    pk.x = (unsigned)tobf(v0) | ((unsigned)tobf(v1) << 16);
    pk.y = (unsigned)tobf(v2) | ((unsigned)tobf(v3) << 16);
    pk.z = (unsigned)tobf(v4) | ((unsigned)tobf(v5) << 16);
    pk.w = (unsigned)tobf(v6) | ((unsigned)tobf(v7) << 16);
    *(uint4*)(Vs + (size_t)rloc * VSS + c * 8) = pk;
}

// shared body: stage W^T, register-chain gather (4 rows x 16 edges in flight,
// 8 lanes/edge, uint4 feature slices, ZROW padding), then 16x16x32 MFMA.
// acc[nt] C/D layout: col=lane&15, row=quad*4+reg (verified).
__device__ __forceinline__ void gcn_core(const uint4* __restrict__ feat16,
                                         const int* __restrict__ csr,
                                         const int* __restrict__ rp,
                                         const float* __restrict__ dinv, float selfw,
                                         const float* __restrict__ W, short* Vs, short* Wt,
                                         int rowBase, int lane, int wave, f32x4 (&acc)[4]) {
    int t = wave * 64 + lane;
    for (int i = t; i < 4096; i += 256) {  // Wt[n][k] = W[k][n], bf16
        int k = i >> 6, n = i & 63;
        Wt[n * VSS + k] = (short)tobf(W[i]);
    }
    __syncthreads();
    int myBase = rowBase + wave * 16;
    int rpv = (lane < 17) ? rp[min(myBase + lane, NODES)] : 0;
    int o = lane >> 3, c = lane & 7;
    for (int ii = 0; ii < 4; ++ii) {
        int rA = ii, rB = ii + 4, rC = ii + 8, rD = ii + 12;
        int begA = __shfl(rpv, rA), cntA = __shfl(rpv, rA + 1) - begA;
        int begB = __shfl(rpv, rB), cntB = __shfl(rpv, rB + 1) - begB;
        int begC = __shfl(rpv, rC), cntC = __shfl(rpv, rC + 1) - begC;
        int begD = __shfl(rpv, rD), cntD = __shfl(rpv, rD + 1) - begD;
        int jmax = max(max(cntA, cntB), max(cntC, cntD));
        float aA[8] = {0, 0, 0, 0, 0, 0, 0, 0};
        float aB[8] = {0, 0, 0, 0, 0, 0, 0, 0};
        float aC[8] = {0, 0, 0, 0, 0, 0, 0, 0};
        float aD[8] = {0, 0, 0, 0, 0, 0, 0, 0};
        for (int j = 0; j < jmax; j += 16) {
            chain_step(feat16, csr, begA, cntA, j, o, c, aA);
            chain_step(feat16, csr, begB, cntB, j, o, c, aB);
            chain_step(feat16, csr, begC, cntC, j, o, c, aC);
            chain_step(feat16, csr, begD, cntD, j, o, c, aD);
            chain_step(feat16, csr, begA, cntA, j + 8, o, c, aA);
            chain_step(feat16, csr, begB, cntB, j + 8, o, c, aB);
            chain_step(feat16, csr, begC, cntC, j + 8, o, c, aC);
            chain_step(feat16, csr, begD, cntD, j + 8, o, c, aD);
        }
        butterfly8(aA);
        butterfly8(aB);
        butterfly8(aC);
        butterfly8(aD);
        if (o == 0) {
            finalize_row(feat16, dinv, selfw, Vs, rowBase, wave * 16 + rA, c, aA);
            finalize_row(feat16, dinv, selfw, Vs, rowBase, wave * 16 + rB, c, aB);
            finalize_row(feat16, dinv, selfw, Vs, rowBase, wave * 16 + rC, c, aC);
            finalize_row(feat16, dinv, selfw, Vs, rowBase, wave * 16 + rD, c, aD);
        }
    }
    frag8 afr[2];
    int m = lane & 15, q = lane >> 4;
#pragma unroll
    for (int ks = 0; ks < 2; ++ks)
        afr[ks] = *(frag8*)(Vs + (size_t)(wave * 16 + m) * VSS + q * 8 + ks * 32);
#pragma unroll
    for (int nt = 0; nt < 4; ++nt) {
        f32x4 a = {0.f, 0.f, 0.f, 0.f};
#pragma unroll
        for (int ks = 0; ks < 2; ++ks) {
            frag8 bfr = *(frag8*)(Wt + (size_t)(nt * 16 + m) * VSS + q * 8 + ks * 32);
            a = __builtin_amdgcn_mfma_f32_16x16x32_bf16(afr[ks], bfr, a, 0, 0, 0);
        }
        acc[nt] = a;
    }
}

// layer1: gather + MFMA + bias + LN + leaky -> h1s = h1*dinv2 (bf16)
__global__ void __launch_bounds__(256, 2)
gcn1_fused(const uint4* __restrict__ xs16, const int* __restrict__ csr,
           const int* __restrict__ rp, const float* __restrict__ dinv1,
           const float* __restrict__ dinv2, const float* __restrict__ W1,
           const float* __restrict__ b1, const float* __restrict__ lng,
           const float* __restrict__ lnb, bf16* __restrict__ h1s) {
    __shared__ __align__(16) short sm[2 * 64 * VSS];
    short* Vs = sm;
    short* Wt = sm + 64 * VSS;
    int lane = threadIdx.x & 63, wave = threadIdx.x >> 6;
    int rowBase = blockIdx.x * 64;
    f32x4 acc[4];
    gcn_core(xs16, csr, rp, dinv1, 2.0f, W1, Vs, Wt, rowBase, lane, wave, acc);
    int c = lane & 15, q = lane >> 4;
    float bc[4], lg[4], lb[4];
#pragma unroll
    for (int nt = 0; nt < 4; ++nt) {
        bc[nt] = b1[nt * 16 + c];
        lg[nt] = lng[nt * 16 + c];
        lb[nt] = lnb[nt * 16 + c];
    }
#pragma unroll
    for (int r = 0; r < 4; ++r) {
        int grow = rowBase + wave * 16 + q * 4 + r;
        float v0 = acc[0][r] + bc[0], v1 = acc[1][r] + bc[1];
        float v2 = acc[2][r] + bc[2], v3 = acc[3][r] + bc[3];
        float s = v0 + v1 + v2 + v3;
        for (int o = 1; o < 16; o <<= 1) s += __shfl_xor(s, o);
        float mu = s * (1.0f / 64.0f);
        float d0 = v0 - mu, d1 = v1 - mu, d2 = v2 - mu, d3 = v3 - mu;
        float qq = d0 * d0 + d1 * d1 + d2 * d2 + d3 * d3;
        for (int o = 1; o < 16; o <<= 1) qq += __shfl_xor(qq, o);
        float rstd = 1.0f / sqrtf(qq * (1.0f / 64.0f) + 1e-5f);
        if (grow < NODES) {
            float d2v = dinv2[grow];
            bf16* dst = h1s + (size_t)grow * 64 + c;
            dst[0]  = __float2bfloat16(lrelu(d0 * rstd * lg[0] + lb[0]) * d2v);
            dst[16] = __float2bfloat16(lrelu(d1 * rstd * lg[1] + lb[1]) * d2v);
            dst[32] = __float2bfloat16(lrelu(d2 * rstd * lg[2] + lb[2]) * d2v);
            dst[48] = __float2bfloat16(lrelu(d3 * rstd * lg[3] + lb[3]) * d2v);
        }
    }
}

// layer2: gather + MFMA + bias + leaky + run-merged max-pool
__global__ void __launch_bounds__(256, 2)
gcn2_fused(const uint4* __restrict__ h1s16, const int* __restrict__ csr,
           const int* __restrict__ rp, const float* __restrict__ dinv2,
           const float* __restrict__ W2, const float* __restrict__ b2,
           const void* __restrict__ batch, const int* __restrict__ flag,
           unsigned* __restrict__ pooled) {
    __shared__ __align__(16) short sm[2 * 64 * VSS];
    __shared__ int gsh[64];
    short* Vs = sm;
    short* Wt = sm + 64 * VSS;
    int t = threadIdx.x, lane = t & 63, wave = t >> 6;
    int rowBase = blockIdx.x * 64;
    if (t < 64) {
        int row = rowBase + t;
        gsh[t] = (row < NODES) ? idx_at(batch, row, flag[0]) : -1;
    }
    f32x4 acc[4];
    gcn_core(h1s16, csr, rp, dinv2, 1.0f, W2, Vs, Wt, rowBase, lane, wave, acc);
    int c = lane & 15, q = lane >> 4;
    float bc[4];
#pragma unroll
    for (int nt = 0; nt < 4; ++nt) bc[nt] = b2[nt * 16 + c];
    __syncthreads();
    float* P = (float*)sm;  // 64 x 65 fp32 pool buffer
#pragma unroll
    for (int r = 0; r < 4; ++r) {
        int mloc = wave * 16 + q * 4 + r;
#pragma unroll
        for (int nt = 0; nt < 4; ++nt)
            P[(size_t)mloc * 65 + nt * 16 + c] = lrelu(acc[nt][r] + bc[nt]);
    }
    __syncthreads();
    if (wave == 0) {
        float m = P[lane];
        int gc = gsh[0];
        for (int r = 1; r < 64; ++r) {
            int gr = gsh[r];
            float ar = P[(size_t)r * 65 + lane];
            if (gr == gc) {
                m = fmaxf(m, ar);
            } else {
                if ((unsigned)gc < NGRAPH) atomicMax(&pooled[gc * 64 + lane], mapf(m));
                gc = gr;
                m = ar;
            }
        }
        if ((unsigned)gc < NGRAPH) atomicMax(&pooled[gc * 64 + lane], mapf(m));
    }
}

// head: z = pooled@W3+b3; LN; leaky; z@W4+b4; softmax. One block per graph.
__global__ void head_kernel(const unsigned* __restrict__ pooled, const float* __restrict__ W3,
                            const float* __restrict__ b3, const float* __restrict__ g2,
                            const float* __restrict__ be2, const float* __restrict__ W4,
                            const float* __restrict__ b4, float* __restrict__ out) {
    __shared__ float prow[64];
    __shared__ float z[768];
    __shared__ float rs[4], rss[4];
    __shared__ float mu_s, rstd_s;
    __shared__ float red[10];
    int t = threadIdx.x, gI = blockIdx.x;
    if (t < 64) prow[t] = unmapf(pooled[gI * 64 + t]);
    __syncthreads();
    for (int c = t; c < 768; c += 256) {
        float acc = b3[c];
#pragma unroll 16
        for (int k = 0; k < 64; ++k) acc += prow[k] * W3[k * 768 + c];
        z[c] = acc;
    }
    __syncthreads();
    float s = 0.0f, ss = 0.0f;
    for (int c = t; c < 768; c += 256) {
        float v = z[c];
        s += v;
        ss += v * v;
    }
    for (int o = 32; o; o >>= 1) {
        s += __shfl_xor(s, o);
        ss += __shfl_xor(ss, o);
    }
    if ((t & 63) == 0) { rs[t >> 6] = s; rss[t >> 6] = ss; }
    __syncthreads();
    if (t == 0) {
        float S = rs[0] + rs[1] + rs[2] + rs[3];
        float SS = rss[0] + rss[1] + rss[2] + rss[3];
        float mu = S * (1.0f / 768.0f);
        float var = SS * (1.0f / 768.0f) - mu * mu;
        mu_s = mu;
        rstd_s = 1.0f / sqrtf(fmaxf(var, 0.0f) + 1e-5f);
    }
    __syncthreads();
    for (int c = t; c < 768; c += 256) {
        float y = (z[c] - mu_s) * rstd_s * g2[c] + be2[c];
        z[c] = lrelu(y);
    }
    if (t < 10) red[t] = 0.0f;
    __syncthreads();
    float p[10];
#pragma unroll
    for (int c = 0; c < 10; ++c) p[c] = 0.0f;
    for (int k = t; k < 768; k += 256) {
        float zv = z[k];
#pragma unroll
        for (int c = 0; c < 10; ++c) p[c] += zv * W4[k * 10 + c];
    }
#pragma unroll
    for (int c = 0; c < 10; ++c) atomicAdd(&red[c], p[c]);
    __syncthreads();
    if (t == 0) {
        float l[10], m = -1e30f;
#pragma unroll
        for (int c = 0; c < 10; ++c) {
            l[c] = red[c] + b4[c];
            m = fmaxf(m, l[c]);
        }
        float sum = 0.0f;
#pragma unroll
        for (int c = 0; c < 10; ++c) {
            l[c] = expf(l[c] - m);
            sum += l[c];
        }
        float inv = 1.0f / sum;
#pragma unroll
        for (int c = 0; c < 10; ++c) out[gI * 10 + c] = l[c] * inv;
    }
}

extern "C" void kernel_launch(void* const* d_in, const int* in_sizes, int n_in,
                              void* d_out, int out_size, void* d_ws, size_t ws_size,
                              hipStream_t stream) {
    const size_t REQUIRED = (size_t)(NODES + 1) * 64 * 2 * 2  // xs + h1s (with ZROW pad)
                          + (size_t)EDGES * 4                 // csr_src
                          + (size_t)(NODES + 1) * 4           // row_ptr
                          + (size_t)NODES * 4 * 2             // dinv1, dinv2
                          + (size_t)NBINS * 4                 // binCursor
                          + (size_t)NGRAPH * 64 * 4           // pooled
                          + 16;                               // flag
    if (ws_size < REQUIRED) {
        sentinel_kernel<<<20, 256, 0, stream>>>((float*)d_out, 64.0f);
        return;
    }

    const float* x = (const float*)d_in[0];
    const int* eiw = (const int*)d_in[1];
    const void* batch = d_in[2];
    const float* W1 = (const float*)d_in[3];
    const float* b1 = (const float*)d_in[4];
    const float* lng = (const float*)d_in[5];
    const float* lnb = (const float*)d_in[6];
    const float* W2 = (const float*)d_in[7];
    const float* b2 = (const float*)d_in[8];
    const float* W3 = (const float*)d_in[9];
    const float* b3 = (const float*)d_in[10];
    const float* g2 = (const float*)d_in[11];
    const float* be2 = (const float*)d_in[12];
    const float* W4 = (const float*)d_in[13];
    const float* b4 = (const float*)d_in[14];

    bf16* xs = (bf16*)d_ws;                               // (N+1)*64 bf16
    bf16* h1s = xs + (size_t)(NODES + 1) * 64;            // (N+1)*64 bf16 (12.8 MB)
    unsigned* staging = (unsigned*)h1s;                   // NBINS*BINCAP*4 = 9.63 MB alias
    int* csr_src = (int*)(h1s + (size_t)(NODES + 1) * 64);  // E
    int* row_ptr = csr_src + EDGES;                       // N+1
    float* dinv1 = (float*)(row_ptr + NODES + 1);         // N
    float* dinv2 = dinv1 + NODES;                         // N
    int* binCursor = (int*)(dinv2 + NODES);               // NBINS
    unsigned* pooled = (unsigned*)(binCursor + NBINS);    // G*64
    int* flag = (int*)(pooled + NGRAPH * 64);             // 1

    // pooled sentinel = 0 (0x00000000 < mapf(v) for every real float v)
    hipMemsetAsync(binCursor, 0, (size_t)NBINS * 4, stream);
    hipMemsetAsync(pooled, 0, (size_t)NGRAPH * 64 * 4, stream);

    // staging build (single edge-pass kernel; fixed-capacity bin slots)
    binPlace<<<NCHUNKS, 256, 0, stream>>>(eiw, flag, binCursor, staging);
    csr_finalize<<<NBINS, 256, 0, stream>>>(staging, binCursor, row_ptr, dinv1, dinv2,
                                            csr_src);
    prescale_x<<<((NODES + 1) * 16 + 255) / 256, 256, 0, stream>>>(x, dinv1, xs, h1s);

    // fused layers: 64 rows/block, 4-chain register gather + MFMA
    gcn1_fused<<<(NODES + 63) / 64, 256, 0, stream>>>((const uint4*)xs, csr_src, row_ptr,
                                                      dinv1, dinv2, W1, b1, lng, lnb, h1s);
    gcn2_fused<<<(NODES + 63) / 64, 256, 0, stream>>>((const uint4*)h1s, csr_src, row_ptr,
                                                      dinv2, W2, b2, batch, flag, pooled);

    // head
    head_kernel<<<NGRAPH, 256, 0, stream>>>(pooled, W3, b3, g2, be2, W4, b4, (float*)d_out);
}